// Round 9
// baseline (302.380 us; speedup 1.0000x reference)
//
#include <hip/hip_runtime.h>

// ---------------------------------------------------------------------------
// GAT 3-layer forward, MI355X (gfx950)
// R9: agg kernels — ALL edge gathers issued before any FMA (16-deep
//     predicated load batch per node, two half-row passes) to maximize
//     memory-level parallelism. GEMMs/ELL/init unchanged (R7-verified).
// ---------------------------------------------------------------------------

typedef __attribute__((ext_vector_type(8))) __bf16 bf16x8;
typedef __attribute__((ext_vector_type(4))) float f32x4;
typedef _Float16 f16x8 __attribute__((ext_vector_type(8)));
typedef _Float16 f16x4 __attribute__((ext_vector_type(4)));

#define NEG_SLOPE 0.2f
#define WELL 40   // ELL row width; P(deg>40) ~ 1e-15 for E/N=6.4 Poisson

__device__ __forceinline__ unsigned short f2b_rne(float f) {
    unsigned int u = __float_as_uint(f);
    u += 0x7FFFu + ((u >> 16) & 1u);
    return (unsigned short)(u >> 16);
}
__device__ __forceinline__ unsigned short f2h(float f) {
    _Float16 h = (_Float16)f;
    unsigned short s;
    __builtin_memcpy(&s, &h, 2);
    return s;
}
__device__ __forceinline__ bf16x8 cvt8(const float* f) {
    unsigned short r[8];
#pragma unroll
    for (int j = 0; j < 8; j++) r[j] = f2b_rne(f[j]);
    bf16x8 v;
    __builtin_memcpy(&v, r, 16);
    return v;
}
__device__ __forceinline__ float lrelu(float e) {
    return e >= 0.f ? e : NEG_SLOPE * e;
}

// ---- init: zero cnt + all W -> Wt [Nout,256] bf16 transposed --------------
__global__ __launch_bounds__(256) void k_init(const float* __restrict__ W1,
                                              const float* __restrict__ W2,
                                              const float* __restrict__ W3,
                                              unsigned short* __restrict__ W1t,
                                              unsigned short* __restrict__ W2t,
                                              unsigned short* __restrict__ W3t,
                                              int* __restrict__ cnt, int n) {
    int t = blockIdx.x * blockDim.x + threadIdx.x;
    if (t < n) cnt[t] = 0;
    const float* W;
    unsigned short* Wt;
    int Nout, idx = t;
    if (idx < 65536)        { W = W1; Wt = W1t; Nout = 256; }
    else if (idx < 131072)  { W = W2; Wt = W2t; Nout = 256; idx -= 65536; }
    else if (idx < 147456)  { W = W3; Wt = W3t; Nout = 64;  idx -= 131072; }
    else return;
    int k = idx / Nout;
    int c = idx - k * Nout;
    Wt[(size_t)c * 256 + k] = f2b_rne(W[idx]);
}

// ---- ELL fill: slot = atomicAdd(cnt[dst]); cnt becomes degree -------------
__global__ __launch_bounds__(256) void k_fillell(const int* __restrict__ src,
                                                 const int* __restrict__ dst,
                                                 int* __restrict__ cnt,
                                                 int* __restrict__ ell, int E) {
    int t = blockIdx.x * blockDim.x + threadIdx.x;
    if (t < E) {
        int d = dst[t];
        int pos = atomicAdd(&cnt[d], 1);
        if (pos < WELL) ell[(size_t)d * WELL + pos] = src[t];
    }
}

// ---- GEMM: h16[M,NT*16] f16 = A[M,256] @ Wt[NT*16,256]^T, fused als/ald ---
// Whole B-slab in LDS (NT*16 x 256 bf16), XOR chunk swizzle, staged once.
// Each wave: 32 rows, whole K in VGPRs, NT*16 cols, barrier-free K-loop.
// Block 512 thr = 8 waves = 256 rows; grid.x = ceil(M/256).
template <int NT, bool AF32>
__global__ __launch_bounds__(512) void k_gemm(const void* __restrict__ Av,
                                              const __bf16* __restrict__ Bt,
                                              unsigned short* __restrict__ h16,
                                              float* __restrict__ als,
                                              float* __restrict__ ald,
                                              const float* __restrict__ a_s,
                                              const float* __restrict__ a_d,
                                              int M, int H) {
    constexpr int NN = NT * 16;
    __shared__ __align__(16) __bf16 Bs[NN][256];

    const int tid = threadIdx.x;
    const int lane = tid & 63;
    const int w = tid >> 6;          // 8 waves
    const int i = lane & 15;
    const int quad = lane >> 4;
    const int m0 = blockIdx.x * 256;

    // ---- stage B slab once; chunk p of row n holds global chunk p^(n&7) ---
    {
        int nl = lane >> 5;          // 0..1
        int p = lane & 31;
#pragma unroll
        for (int t = 0; t < NN / 16; t++) {
            int n = t * 16 + w * 2 + nl;
            int g = p ^ (n & 7);
            const __bf16* gp = Bt + (size_t)n * 256 + g * 8;
            __builtin_amdgcn_global_load_lds(
                (const __attribute__((address_space(1))) void*)gp,
                (__attribute__((address_space(3))) void*)&Bs[t * 16 + w * 2][0],
                16, 0, 0);
        }
    }

    // ---- load whole-K A strips into registers -----------------------------
    int ra = m0 + w * 32 + i;
    int rb = ra + 16;
    if (ra >= M) ra = M - 1;
    if (rb >= M) rb = M - 1;

    bf16x8 afrag[2][8];   // [strip][kc]
    if (AF32) {
        const float* pa = (const float*)Av + (size_t)ra * 256;
        const float* pb = (const float*)Av + (size_t)rb * 256;
#pragma unroll
        for (int half = 0; half < 2; half++) {
            float tmp[2][4][8];
#pragma unroll
            for (int k4 = 0; k4 < 4; k4++) {
                int koff = (half * 4 + k4) * 32 + quad * 8;
                *(float4*)&tmp[0][k4][0] = *(const float4*)(pa + koff);
                *(float4*)&tmp[0][k4][4] = *(const float4*)(pa + koff + 4);
                *(float4*)&tmp[1][k4][0] = *(const float4*)(pb + koff);
                *(float4*)&tmp[1][k4][4] = *(const float4*)(pb + koff + 4);
            }
#pragma unroll
            for (int k4 = 0; k4 < 4; k4++) {
                afrag[0][half * 4 + k4] = cvt8(tmp[0][k4]);
                afrag[1][half * 4 + k4] = cvt8(tmp[1][k4]);
            }
        }
    } else {
        const __bf16* pa = (const __bf16*)Av + (size_t)ra * 256;
        const __bf16* pb = (const __bf16*)Av + (size_t)rb * 256;
#pragma unroll
        for (int kc = 0; kc < 8; kc++) {
            int koff = kc * 32 + quad * 8;
            afrag[0][kc] = *(const bf16x8*)(pa + koff);
            afrag[1][kc] = *(const bf16x8*)(pb + koff);
        }
    }

    f32x4 acc[2][NT] = {};

    __syncthreads();   // B slab ready; no more barriers

#pragma unroll
    for (int kc = 0; kc < 8; kc++) {
        const int c = kc * 4 + quad;
#pragma unroll
        for (int nt = 0; nt < NT; nt++) {
            const int n = nt * 16 + i;
            const int p = c ^ (n & 7);
            bf16x8 bfv = *(const bf16x8*)&Bs[n][p * 8];
            acc[0][nt] = __builtin_amdgcn_mfma_f32_16x16x32_bf16(
                afrag[0][kc], bfv, acc[0][nt], 0, 0, 0);
            acc[1][nt] = __builtin_amdgcn_mfma_f32_16x16x32_bf16(
                afrag[1][kc], bfv, acc[1][nt], 0, 0, 0);
        }
    }

    // ---- epilogue: C/D map col=lane&15, row=quad*4+reg --------------------
    float asv[NT], adv[NT];
#pragma unroll
    for (int nt = 0; nt < NT; nt++) {
        asv[nt] = a_s[(nt / 4) * 64 + (nt & 3) * 16 + i];
        adv[nt] = a_d[(nt / 4) * 64 + (nt & 3) * 16 + i];
    }

#pragma unroll
    for (int mt = 0; mt < 2; mt++) {
#pragma unroll
        for (int r = 0; r < 4; r++) {
            int row = m0 + w * 32 + mt * 16 + quad * 4 + r;
            bool ok = row < M;
#pragma unroll
            for (int nt = 0; nt < NT; nt++) {
                if (ok) h16[(size_t)row * NN + nt * 16 + i] = f2h(acc[mt][nt][r]);
            }
#pragma unroll
            for (int g = 0; g < (NT + 3) / 4; g++) {
                float ps = 0.f, pd = 0.f;
#pragma unroll
                for (int j = 0; j < 4 && g * 4 + j < NT; j++) {
                    float v = acc[mt][g * 4 + j][r];
                    ps += v * asv[g * 4 + j];
                    pd += v * adv[g * 4 + j];
                }
#pragma unroll
                for (int off = 1; off <= 8; off <<= 1) {
                    ps += __shfl_xor(ps, off, 64);
                    pd += __shfl_xor(pd, off, 64);
                }
                if (ok && i == 0) {
                    als[(size_t)row * H + g] = ps;
                    ald[(size_t)row * H + g] = pd;
                }
            }
        }
    }
}

// ---- aggregation, H=4 C=64: 4 nodes/wave, 16-deep batched gathers ---------
__global__ __launch_bounds__(256) void k_agg4(const unsigned short* __restrict__ h16,
                                              const float* __restrict__ als,
                                              const float* __restrict__ ald,
                                              const int* __restrict__ cnt,
                                              const int* __restrict__ ell,
                                              const float* __restrict__ bias,
                                              unsigned short* __restrict__ xout,
                                              int n) {
    int gw = (blockIdx.x * blockDim.x + threadIdx.x) >> 6;
    int lane = threadIdx.x & 63;
    int wid = gw * 4 + (lane >> 4);
    if (wid >= n) return;
    int l = lane & 15;
    int head = l >> 2;       // 4 lanes per head
    int ch = l * 16;         // 16 f16 channels per lane
    int base = lane & 48;    // node-group base lane for shfl

    int deg = min(cnt[wid], WELL);
    const int* row = ell + (size_t)wid * WELL;
    int myid = (l < deg) ? row[l] : 0;   // cooperative id prefetch, slots 0..15
    int dm1 = deg - 1;

    // own-node term
    float aldv = ald[wid * 4 + head];
    float p = __expf(fminf(lrelu(als[wid * 4 + head] + aldv), 60.f));
    float ssum = p;
    float a[16];
    {
        f16x8 h0 = *(const f16x8*)&h16[(size_t)wid * 256 + ch];
        f16x8 h1 = *(const f16x8*)&h16[(size_t)wid * 256 + ch + 8];
#pragma unroll
        for (int j = 0; j < 8; j++) { a[j] = p * (float)h0[j]; a[8 + j] = p * (float)h1[j]; }
    }

    // all edge ids via shfl (dup-last for inactive slots)
    int sid[16];
#pragma unroll
    for (int j = 0; j < 16; j++) sid[j] = __shfl(myid, base + min(j, dm1));

    // batch 1: all als gathers -> exp weights (predicated; 0 for j>=deg)
    float pw[16];
#pragma unroll
    for (int j = 0; j < 16; j++) {
        float e = 0.f;
        if (j < deg) e = als[sid[j] * 4 + head];
        pw[j] = (j < deg) ? __expf(fminf(lrelu(e + aldv), 60.f)) : 0.f;
        ssum += pw[j];
    }

    // batch 2: half-row A — all loads first, then guarded FMA groups
    {
        f16x8 v[16];
#pragma unroll
        for (int j = 0; j < 16; j++) {
            v[j] = f16x8{};
            if (j < deg) v[j] = *(const f16x8*)&h16[(size_t)sid[j] * 256 + ch];
        }
#pragma unroll
        for (int j = 0; j < 16; j += 4) {
            if (j < deg) {
#pragma unroll
                for (int k = 0; k < 8; k++)
                    a[k] += (pw[j] * (float)v[j][k] + pw[j + 1] * (float)v[j + 1][k]) +
                            (pw[j + 2] * (float)v[j + 2][k] + pw[j + 3] * (float)v[j + 3][k]);
            }
        }
    }
    // batch 3: half-row B
    {
        f16x8 v[16];
#pragma unroll
        for (int j = 0; j < 16; j++) {
            v[j] = f16x8{};
            if (j < deg) v[j] = *(const f16x8*)&h16[(size_t)sid[j] * 256 + ch + 8];
        }
#pragma unroll
        for (int j = 0; j < 16; j += 4) {
            if (j < deg) {
#pragma unroll
                for (int k = 0; k < 8; k++)
                    a[8 + k] += (pw[j] * (float)v[j][k] + pw[j + 1] * (float)v[j + 1][k]) +
                                (pw[j + 2] * (float)v[j + 2][k] + pw[j + 3] * (float)v[j + 3][k]);
            }
        }
    }

    // rare tail: deg > 16
    for (int j = 16; j < deg; ++j) {
        int s0 = row[j];
        float p0 = __expf(fminf(lrelu(als[s0 * 4 + head] + aldv), 60.f));
        f16x8 v0a = *(const f16x8*)&h16[(size_t)s0 * 256 + ch];
        f16x8 v0b = *(const f16x8*)&h16[(size_t)s0 * 256 + ch + 8];
        ssum += p0;
#pragma unroll
        for (int k = 0; k < 8; k++) {
            a[k] += p0 * (float)v0a[k];
            a[8 + k] += p0 * (float)v0b[k];
        }
    }

    float inv = 1.f / (ssum + 1e-16f);
    float bb[16];
#pragma unroll
    for (int q = 0; q < 4; q++)
        *(float4*)&bb[q * 4] = *(const float4*)&bias[ch + q * 4];
    unsigned short o[16];
#pragma unroll
    for (int k = 0; k < 16; k++) {
        float r = a[k] * inv + bb[k];
        r = r > 0.f ? r : expm1f(r);
        o[k] = f2b_rne(r);
    }
    *(int4*)&xout[(size_t)wid * 256 + ch] = *(const int4*)&o[0];
    *(int4*)&xout[(size_t)wid * 256 + ch + 8] = *(const int4*)&o[8];
}

// ---- aggregation, H=1 C=64, final: 16-deep batched gathers, f32 out -------
__global__ __launch_bounds__(256) void k_agg1(const unsigned short* __restrict__ h16,
                                              const float* __restrict__ als,
                                              const float* __restrict__ ald,
                                              const int* __restrict__ cnt,
                                              const int* __restrict__ ell,
                                              const float* __restrict__ bias,
                                              float* __restrict__ out, int n) {
    int gw = (blockIdx.x * blockDim.x + threadIdx.x) >> 6;
    int lane = threadIdx.x & 63;
    int wid = gw * 4 + (lane >> 4);
    if (wid >= n) return;
    int l = lane & 15;
    int ch = l * 4;
    int base = lane & 48;

    int deg = min(cnt[wid], WELL);
    const int* row = ell + (size_t)wid * WELL;
    int myid = (l < deg) ? row[l] : 0;
    int dm1 = deg - 1;

    float aldv = ald[wid];
    float p = __expf(fminf(lrelu(als[wid] + aldv), 60.f));
    float ssum = p;
    float a[4];
    {
        f16x4 hv = *(const f16x4*)&h16[(size_t)wid * 64 + ch];
#pragma unroll
        for (int k = 0; k < 4; k++) a[k] = p * (float)hv[k];
    }

    int sid[16];
#pragma unroll
    for (int j = 0; j < 16; j++) sid[j] = __shfl(myid, base + min(j, dm1));

    float pw[16];
#pragma unroll
    for (int j = 0; j < 16; j++) {
        float e = 0.f;
        if (j < deg) e = als[sid[j]];
        pw[j] = (j < deg) ? __expf(fminf(lrelu(e + aldv), 60.f)) : 0.f;
        ssum += pw[j];
    }

    {
        f16x4 v[16];
#pragma unroll
        for (int j = 0; j < 16; j++) {
            v[j] = f16x4{};
            if (j < deg) v[j] = *(const f16x4*)&h16[(size_t)sid[j] * 64 + ch];
        }
#pragma unroll
        for (int j = 0; j < 16; j += 4) {
            if (j < deg) {
#pragma unroll
                for (int k = 0; k < 4; k++)
                    a[k] += (pw[j] * (float)v[j][k] + pw[j + 1] * (float)v[j + 1][k]) +
                            (pw[j + 2] * (float)v[j + 2][k] + pw[j + 3] * (float)v[j + 3][k]);
            }
        }
    }

    for (int j = 16; j < deg; ++j) {
        int s0 = row[j];
        float p0 = __expf(fminf(lrelu(als[s0] + aldv), 60.f));
        f16x4 v0 = *(const f16x4*)&h16[(size_t)s0 * 64 + ch];
        ssum += p0;
#pragma unroll
        for (int k = 0; k < 4; k++) a[k] += p0 * (float)v0[k];
    }
    float inv = 1.f / (ssum + 1e-16f);
    float4 bv = *(const float4*)&bias[ch];
    float4 r;
    r.x = a[0] * inv + bv.x;
    r.y = a[1] * inv + bv.y;
    r.z = a[2] * inv + bv.z;
    r.w = a[3] * inv + bv.w;
    *(float4*)&out[(size_t)wid * 64 + ch] = r;
}

// ---------------------------------------------------------------------------
extern "C" void kernel_launch(void* const* d_in, const int* in_sizes, int n_in,
                              void* d_out, int out_size, void* d_ws, size_t ws_size,
                              hipStream_t stream) {
    const float* x   = (const float*)d_in[0];
    const int*   ei  = (const int*)d_in[1];
    const float* W1  = (const float*)d_in[2];
    const float* as1 = (const float*)d_in[3];
    const float* ad1 = (const float*)d_in[4];
    const float* b1  = (const float*)d_in[5];
    const float* W2  = (const float*)d_in[6];
    const float* as2 = (const float*)d_in[7];
    const float* ad2 = (const float*)d_in[8];
    const float* b2  = (const float*)d_in[9];
    const float* W3  = (const float*)d_in[10];
    const float* as3 = (const float*)d_in[11];
    const float* ad3 = (const float*)d_in[12];
    const float* b3  = (const float*)d_in[13];

    const int N = in_sizes[0] / 256;   // 50000
    const int E = in_sizes[1] / 2;     // 320000

    size_t off = 0;
    auto alloc = [&](size_t bytes) -> void* {
        void* p = (char*)d_ws + off;
        off += (bytes + 255) & ~(size_t)255;
        return p;
    };
    unsigned short* xb  = (unsigned short*)alloc((size_t)N * 256 * 2);
    unsigned short* W1t = (unsigned short*)alloc((size_t)256 * 256 * 2);
    unsigned short* W2t = (unsigned short*)alloc((size_t)256 * 256 * 2);
    unsigned short* W3t = (unsigned short*)alloc((size_t)64 * 256 * 2);
    unsigned short* h16 = (unsigned short*)alloc((size_t)N * 256 * 2);
    float* als = (float*)alloc((size_t)N * 4 * 4);
    float* ald = (float*)alloc((size_t)N * 4 * 4);
    int* cnt   = (int*)alloc((size_t)N * 4);
    int* ell   = (int*)alloc((size_t)N * WELL * 4);

    const int T = 256;
    const int agg_blocks = (N + 15) / 16;   // 4 nodes/wave, 4 waves/block
    const int mtiles = (N + 255) / 256;     // 196

    // init: zero cnt + W conversions (one launch)
    k_init<<<dim3(576), T, 0, stream>>>(W1, W2, W3, W1t, W2t, W3t, cnt, N);

    // ELL adjacency fill (dst-grouped); self-loop handled analytically in agg
    k_fillell<<<dim3((E + T - 1) / T), T, 0, stream>>>(ei, ei + E, cnt, ell, E);

    // layer 1 (A = x in f32, converted in-kernel)
    k_gemm<16, true><<<dim3(mtiles), 512, 0, stream>>>(x, (const __bf16*)W1t,
                                                       h16, als, ald, as1, ad1, N, 4);
    k_agg4<<<dim3(agg_blocks), T, 0, stream>>>(h16, als, ald, cnt, ell, b1, xb, N);

    // layer 2
    k_gemm<16, false><<<dim3(mtiles), 512, 0, stream>>>(xb, (const __bf16*)W2t,
                                                        h16, als, ald, as2, ad2, N, 4);
    k_agg4<<<dim3(agg_blocks), T, 0, stream>>>(h16, als, ald, cnt, ell, b2, xb, N);

    // layer 3 (H=1, C=64)
    k_gemm<4, false><<<dim3(mtiles), 512, 0, stream>>>(xb, (const __bf16*)W3t,
                                                       h16, als, ald, as3, ad3, N, 1);
    k_agg1<<<dim3(agg_blocks), T, 0, stream>>>(h16, als, ald, cnt, ell, b3,
                                               (float*)d_out, N);
}